// Round 2
// baseline (1837.970 us; speedup 1.0000x reference)
//
#include <hip/hip_runtime.h>
#include <math.h>

// ---------------- problem constants ----------------
constexpr int kDIM   = 192;
constexpr int kH     = 56;
constexpr int kW     = 56;
constexpr int kWS    = 7;
constexpr int kSHIFT = 3;
constexpr int kNH    = 6;
constexpr int kHD    = 32;            // DIM / NH
constexpr int kN     = 49;            // WS*WS
constexpr int kNW    = 64;            // (H/WS)^2
constexpr int kB     = 32;
constexpr int kL     = kH * kW;       // 3136
constexpr int kBw    = kB * kNW;      // 2048 windows
constexpr int kROWS  = kBw * kN;      // 100352 = B*L
constexpr int kMLP   = 768;
constexpr int kCHUNK = kROWS / 4;     // 25088 rows per MLP chunk
constexpr float kSCALE = 0.17677669529663687f;   // 32^-0.5
constexpr long  SZf  = (long)kROWS * kDIM;       // 19,267,584 floats = one 77MB slot

// ---------------- LayerNorm (optionally fused roll + window partition) ----------------
// GATHER=true : output row r is in window order (bw*49+n); source gathered from
//               rolled position. GATHER=false: natural token order.
template<bool GATHER>
__global__ __launch_bounds__(256) void ln_kernel(const float* __restrict__ x,
                                                 const float* __restrict__ w,
                                                 const float* __restrict__ b,
                                                 float* __restrict__ out) {
  const int wave = threadIdx.x >> 6;
  const int lane = threadIdx.x & 63;
  const int r = blockIdx.x * 4 + wave;          // 0..100351
  long src, dst;
  if (GATHER) {
    const int bw = r / kN, n = r % kN;
    const int bb = bw >> 6, wdx = bw & 63;
    const int wh = wdx >> 3, ww = wdx & 7;
    const int i = n / kWS, j = n % kWS;
    const int hs = (wh * kWS + i + kSHIFT) % kH;   // roll by -3: rolled[h]=x[h+3]
    const int cs = (ww * kWS + j + kSHIFT) % kW;
    src = ((long)bb * kL + hs * kW + cs) * kDIM;
    dst = (long)r * kDIM;
  } else {
    src = (long)r * kDIM;
    dst = src;
  }
  const float v0 = x[src + lane];
  const float v1 = x[src + lane + 64];
  const float v2 = x[src + lane + 128];
  float s = v0 + v1 + v2;
  #pragma unroll
  for (int m = 1; m < 64; m <<= 1) s += __shfl_xor(s, m, 64);
  const float mu = s * (1.0f / 192.0f);
  const float d0 = v0 - mu, d1 = v1 - mu, d2 = v2 - mu;
  float vs = d0 * d0 + d1 * d1 + d2 * d2;
  #pragma unroll
  for (int m = 1; m < 64; m <<= 1) vs += __shfl_xor(vs, m, 64);
  const float inv = rsqrtf(vs * (1.0f / 192.0f) + 1e-5f);
  out[dst + lane]       = d0 * inv * w[lane]       + b[lane];
  out[dst + lane + 64]  = d1 * inv * w[lane + 64]  + b[lane + 64];
  out[dst + lane + 128] = d2 * inv * w[lane + 128] + b[lane + 128];
}

// ---------------- generic fp32 GEMM: C[r][c] = sum_k A[r][k]*W[c][k] (+epilogue) ----------------
// 64x64 tile, BK=32, 4x4 per thread, 256 threads.
// EPI 0: QKV  -> scatter to q/k/v (window,head,token,d), q *= SCALE. out = q base.
// EPI 1: proj -> window-reverse + roll(+3) + residual(resid = x) -> out (natural order)
// EPI 2: FC1  -> exact GELU -> out (stride 768)
// EPI 3: FC2  -> + resid -> out (stride 192)
template<int KTOT, int EPI>
__global__ __launch_bounds__(256) void gemm64(const float* __restrict__ A,
                                              const float* __restrict__ W,
                                              const float* __restrict__ bias,
                                              const float* __restrict__ resid,
                                              float* __restrict__ out) {
  __shared__ float As[32][68];   // [k][m], pitch 68 floats keeps 16B alignment + spreads banks
  __shared__ float Bs[32][68];   // [k][n]
  const int t    = threadIdx.x;
  const int row0 = blockIdx.x * 64;
  const int col0 = blockIdx.y * 64;
  const int tm   = t >> 4;          // 0..15
  const int tn   = t & 15;          // 0..15
  const int lr   = t >> 3;          // 0..31 (load row within half-tile)
  const int lc   = (t & 7) * 4;     // 0..28 (load col, float4)

  float acc[4][4] = {};

  for (int k0 = 0; k0 < KTOT; k0 += 32) {
    const float4 a0 = *reinterpret_cast<const float4*>(&A[(long)(row0 + lr)      * KTOT + k0 + lc]);
    const float4 a1 = *reinterpret_cast<const float4*>(&A[(long)(row0 + lr + 32) * KTOT + k0 + lc]);
    const float4 b0 = *reinterpret_cast<const float4*>(&W[(long)(col0 + lr)      * KTOT + k0 + lc]);
    const float4 b1 = *reinterpret_cast<const float4*>(&W[(long)(col0 + lr + 32) * KTOT + k0 + lc]);
    __syncthreads();                 // previous iteration's reads done
    As[lc + 0][lr] = a0.x; As[lc + 1][lr] = a0.y; As[lc + 2][lr] = a0.z; As[lc + 3][lr] = a0.w;
    As[lc + 0][lr + 32] = a1.x; As[lc + 1][lr + 32] = a1.y; As[lc + 2][lr + 32] = a1.z; As[lc + 3][lr + 32] = a1.w;
    Bs[lc + 0][lr] = b0.x; Bs[lc + 1][lr] = b0.y; Bs[lc + 2][lr] = b0.z; Bs[lc + 3][lr] = b0.w;
    Bs[lc + 0][lr + 32] = b1.x; Bs[lc + 1][lr + 32] = b1.y; Bs[lc + 2][lr + 32] = b1.z; Bs[lc + 3][lr + 32] = b1.w;
    __syncthreads();
    #pragma unroll
    for (int kk = 0; kk < 32; ++kk) {
      const float4 av = *reinterpret_cast<const float4*>(&As[kk][tm * 4]);
      const float4 bv = *reinterpret_cast<const float4*>(&Bs[kk][tn * 4]);
      const float aarr[4] = {av.x, av.y, av.z, av.w};
      const float barr[4] = {bv.x, bv.y, bv.z, bv.w};
      #pragma unroll
      for (int i = 0; i < 4; ++i)
        #pragma unroll
        for (int j = 0; j < 4; ++j)
          acc[i][j] += aarr[i] * barr[j];
    }
  }

  const int c0 = col0 + tn * 4;
  const float4 bv4 = *reinterpret_cast<const float4*>(&bias[c0]);
  const float bb4[4] = {bv4.x, bv4.y, bv4.z, bv4.w};

  if constexpr (EPI == 0) {
    const int which = c0 / kDIM;              // 0=q 1=k 2=v (constant over the 4 cols)
    const int hd    = (c0 % kDIM) >> 5;
    const int d0    = c0 & 31;
    const float sc  = (which == 0) ? kSCALE : 1.0f;
    #pragma unroll
    for (int i = 0; i < 4; ++i) {
      const int r  = row0 + tm * 4 + i;
      const int bw = r / kN, n = r % kN;
      float4 v;
      v.x = (acc[i][0] + bb4[0]) * sc;
      v.y = (acc[i][1] + bb4[1]) * sc;
      v.z = (acc[i][2] + bb4[2]) * sc;
      v.w = (acc[i][3] + bb4[3]) * sc;
      *reinterpret_cast<float4*>(&out[(long)which * SZf + (((long)bw * kNH + hd) * kN + n) * kHD + d0]) = v;
    }
  } else if constexpr (EPI == 1) {
    #pragma unroll
    for (int i = 0; i < 4; ++i) {
      const int r   = row0 + tm * 4 + i;
      const int bw  = r / kN, n = r % kN;
      const int bb  = bw >> 6, wdx = bw & 63;
      const int wh  = wdx >> 3, ww = wdx & 7;
      const int ii  = n / kWS, jj = n % kWS;
      const int hf  = (wh * kWS + ii + kSHIFT) % kH;   // roll back (+3)
      const int wf  = (ww * kWS + jj + kSHIFT) % kW;
      const long dst = ((long)bb * kL + hf * kW + wf) * kDIM + c0;
      const float4 rv = *reinterpret_cast<const float4*>(&resid[dst]);
      float4 v;
      v.x = rv.x + acc[i][0] + bb4[0];
      v.y = rv.y + acc[i][1] + bb4[1];
      v.z = rv.z + acc[i][2] + bb4[2];
      v.w = rv.w + acc[i][3] + bb4[3];
      *reinterpret_cast<float4*>(&out[dst]) = v;
    }
  } else if constexpr (EPI == 2) {
    #pragma unroll
    for (int i = 0; i < 4; ++i) {
      const int r = row0 + tm * 4 + i;
      float4 v;
      float t0 = acc[i][0] + bb4[0];
      float t1 = acc[i][1] + bb4[1];
      float t2 = acc[i][2] + bb4[2];
      float t3 = acc[i][3] + bb4[3];
      v.x = 0.5f * t0 * (1.0f + erff(t0 * 0.7071067811865476f));
      v.y = 0.5f * t1 * (1.0f + erff(t1 * 0.7071067811865476f));
      v.z = 0.5f * t2 * (1.0f + erff(t2 * 0.7071067811865476f));
      v.w = 0.5f * t3 * (1.0f + erff(t3 * 0.7071067811865476f));
      *reinterpret_cast<float4*>(&out[(long)r * kMLP + c0]) = v;
    }
  } else {  // EPI == 3
    #pragma unroll
    for (int i = 0; i < 4; ++i) {
      const int r = row0 + tm * 4 + i;
      const long dst = (long)r * kDIM + c0;
      const float4 rv = *reinterpret_cast<const float4*>(&resid[dst]);
      float4 v;
      v.x = rv.x + acc[i][0] + bb4[0];
      v.y = rv.y + acc[i][1] + bb4[1];
      v.z = rv.z + acc[i][2] + bb4[2];
      v.w = rv.w + acc[i][3] + bb4[3];
      *reinterpret_cast<float4*>(&out[dst]) = v;
    }
  }
}

// ---------------- attention: one block per (window, head) ----------------
// q pre-scaled by SCALE. rel-pos bias + shift mask computed inline.
__global__ __launch_bounds__(256) void attn_kernel(const float* __restrict__ qkv,  // q|k|v, each SZf
                                                   const float* __restrict__ rpb,  // (169, 6)
                                                   float* __restrict__ out) {      // (Bw*49, 192)
  __shared__ float qs[kN * 33];
  __shared__ float ks[kN * 33];
  __shared__ float vs[kN * 33];
  __shared__ float ss[kN * kN];
  const int bw   = blockIdx.x;
  const int head = blockIdx.y;
  const long base = ((long)bw * kNH + head) * (kN * kHD);
  const float* qg = qkv + base;
  const float* kg = qkv + SZf + base;
  const float* vg = qkv + 2 * SZf + base;
  for (int g = threadIdx.x; g < kN * kHD; g += 256) {
    const int n = g >> 5, d = g & 31;
    qs[n * 33 + d] = qg[g];
    ks[n * 33 + d] = kg[g];
    vs[n * 33 + d] = vg[g];
  }
  __syncthreads();

  const int wdx = bw & 63;
  const int wh = wdx >> 3, ww = wdx & 7;

  // S = q k^T (+bias +mask)
  for (int e = threadIdx.x; e < kN * kN; e += 256) {
    const int n = e / kN, m = e % kN;
    float acc = 0.0f;
    #pragma unroll
    for (int d = 0; d < kHD; ++d) acc += qs[n * 33 + d] * ks[m * 33 + d];
    const int in_ = n / kWS, jn = n % kWS;
    const int im  = m / kWS, jm = m % kWS;
    acc += rpb[((in_ - im + 6) * 13 + (jn - jm + 6)) * kNH + head];
    const int hn = wh * kWS + in_, cn = ww * kWS + jn;
    const int hm = wh * kWS + im,  cm = ww * kWS + jm;
    const int lab_n = (hn < 49 ? 0 : (hn < 53 ? 1 : 2)) * 3 + (cn < 49 ? 0 : (cn < 53 ? 1 : 2));
    const int lab_m = (hm < 49 ? 0 : (hm < 53 ? 1 : 2)) * 3 + (cm < 49 ? 0 : (cm < 53 ? 1 : 2));
    if (lab_n != lab_m) acc -= 100.0f;
    ss[e] = acc;
  }
  __syncthreads();

  // softmax: one wave per row
  const int wave = threadIdx.x >> 6, lane = threadIdx.x & 63;
  for (int n = wave; n < kN; n += 4) {
    const float val = (lane < kN) ? ss[n * kN + lane] : -1e30f;
    float mx = val;
    #pragma unroll
    for (int m = 1; m < 64; m <<= 1) mx = fmaxf(mx, __shfl_xor(mx, m, 64));
    const float e = (lane < kN) ? __expf(val - mx) : 0.0f;
    float sum = e;
    #pragma unroll
    for (int m = 1; m < 64; m <<= 1) sum += __shfl_xor(sum, m, 64);
    if (lane < kN) ss[n * kN + lane] = e / sum;
  }
  __syncthreads();

  // O = P v  -> out[(bw*49+n)*192 + head*32 + d]
  const int n0 = threadIdx.x >> 5, d = threadIdx.x & 31;
  for (int n = n0; n < kN; n += 8) {
    float acc = 0.0f;
    #pragma unroll
    for (int m = 0; m < kN; ++m) acc += ss[n * kN + m] * vs[m * 33 + d];
    out[((long)bw * kN + n) * kDIM + head * kHD + d] = acc;
  }
}

// ---------------- launcher ----------------
// ws layout (slots of SZf floats = 77MB). Peak use = 4 slots = 308 MB:
//   slot0: xw (LN1+windowed) -> reused as attn_out
//   slot1: q  -> reused as h2 (LN2 out)
//   slot2: k  -> reused as m1 (FC1 chunk activation, 25088x768 = 1 slot)
//   slot3: v
// X1 (attn residual output) lives in d_out.
extern "C" void kernel_launch(void* const* d_in, const int* in_sizes, int n_in,
                              void* d_out, int out_size, void* d_ws, size_t ws_size,
                              hipStream_t stream) {
  const float* x     = (const float*)d_in[0];
  const float* n1w   = (const float*)d_in[1];
  const float* n1b   = (const float*)d_in[2];
  const float* qkvw  = (const float*)d_in[3];
  const float* qkvb  = (const float*)d_in[4];
  const float* rpb   = (const float*)d_in[5];
  const float* projw = (const float*)d_in[6];
  const float* projb = (const float*)d_in[7];
  const float* n2w   = (const float*)d_in[8];
  const float* n2b   = (const float*)d_in[9];
  const float* fc1w  = (const float*)d_in[10];
  const float* fc1b  = (const float*)d_in[11];
  const float* fc2w  = (const float*)d_in[12];
  const float* fc2b  = (const float*)d_in[13];
  float* outp = (float*)d_out;
  float* ws   = (float*)d_ws;

  float* xw     = ws;                 // slot 0
  float* qb     = ws + SZf;           // slots 1..3 (q,k,v)
  float* attn_o = ws;                 // slot 0 (xw dead)
  float* h2     = ws + SZf;           // slot 1 (q dead)
  float* m1     = ws + 2 * SZf;       // slot 2 (k dead) — one MLP chunk

  // 1. LN1 + roll(-3,-3) + window partition
  ln_kernel<true><<<dim3(kROWS / 4), dim3(256), 0, stream>>>(x, n1w, n1b, xw);
  // 2. QKV GEMM (scatter epilogue, q pre-scaled)
  gemm64<192, 0><<<dim3(kROWS / 64, 9), dim3(256), 0, stream>>>(xw, qkvw, qkvb, nullptr, qb);
  // 3. attention per (window, head)
  attn_kernel<<<dim3(kBw, kNH), dim3(256), 0, stream>>>(qb, rpb, attn_o);
  // 4. proj GEMM + window reverse + roll(+3,+3) + residual -> X1 (in d_out)
  gemm64<192, 1><<<dim3(kROWS / 64, 3), dim3(256), 0, stream>>>(attn_o, projw, projb, x, outp);
  // 5. LN2
  ln_kernel<false><<<dim3(kROWS / 4), dim3(256), 0, stream>>>(outp, n2w, n2b, h2);
  // 6+7. MLP in 4 row-chunks: FC1+GELU -> m1 (1 slot), FC2 + residual -> outp
  for (int c = 0; c < 4; ++c) {
    const long ro = (long)c * kCHUNK;
    gemm64<192, 2><<<dim3(kCHUNK / 64, 12), dim3(256), 0, stream>>>(
        h2 + ro * kDIM, fc1w, fc1b, nullptr, m1);
    gemm64<768, 3><<<dim3(kCHUNK / 64, 3), dim3(256), 0, stream>>>(
        m1, fc2w, fc2b, outp + ro * kDIM, outp + ro * kDIM);
  }
}

// Round 3
// 1053.193 us; speedup vs baseline: 1.7451x; 1.7451x over previous
//
#include <hip/hip_runtime.h>
#include <math.h>

// ---------------- problem constants ----------------
constexpr int kDIM   = 192;
constexpr int kH     = 56;
constexpr int kW     = 56;
constexpr int kWS    = 7;
constexpr int kSHIFT = 3;
constexpr int kNH    = 6;
constexpr int kHD    = 32;            // DIM / NH
constexpr int kN     = 49;            // WS*WS
constexpr int kB     = 32;
constexpr int kL     = kH * kW;       // 3136
constexpr int kBw    = kB * 64;       // 2048 windows
constexpr int kROWS  = kBw * kN;      // 100352 = B*L
constexpr int kMLP   = 768;
constexpr int kCHUNK = kROWS / 4;     // 25088 rows per MLP chunk
constexpr float kSCALE = 0.17677669529663687f;   // 32^-0.5
constexpr long  SZf  = (long)kROWS * kDIM;       // 19,267,584 elements per slot

typedef unsigned short u16;
typedef __attribute__((ext_vector_type(8))) short bf16x8;   // 8 bf16 = 4 VGPRs
typedef __attribute__((ext_vector_type(4))) float f32x4;

__device__ __forceinline__ u16 f2bf(float f) {              // RNE float->bf16
  unsigned u = __float_as_uint(f);
  u += 0x7fff + ((u >> 16) & 1);
  return (u16)(u >> 16);
}
__device__ __forceinline__ float bf2f(u16 h) {
  return __uint_as_float(((unsigned)h) << 16);
}

// ---------------- weight conversion (fp32 -> bf16, all 4 mats) ----------------
__global__ __launch_bounds__(256) void convert_weights(const float* __restrict__ qkvw,
                                                       const float* __restrict__ projw,
                                                       const float* __restrict__ fc1w,
                                                       const float* __restrict__ fc2w,
                                                       u16* __restrict__ out) {
  const int i = blockIdx.x * 256 + threadIdx.x;   // total 442368
  float v;
  if (i < 110592)       v = qkvw[i];
  else if (i < 147456)  v = projw[i - 110592];
  else if (i < 294912)  v = fc1w[i - 147456];
  else                  v = fc2w[i - 294912];
  out[i] = f2bf(v);
}

// ---------------- LayerNorm -> bf16 (optionally fused roll + window partition) ----------------
template<bool GATHER>
__global__ __launch_bounds__(256) void ln_kernel(const float* __restrict__ x,
                                                 const float* __restrict__ w,
                                                 const float* __restrict__ b,
                                                 u16* __restrict__ out) {
  const int wave = threadIdx.x >> 6;
  const int lane = threadIdx.x & 63;
  const int r = blockIdx.x * 4 + wave;          // 0..100351
  long src, dst;
  if (GATHER) {
    const int bw = r / kN, n = r % kN;
    const int bb = bw >> 6, wdx = bw & 63;
    const int wh = wdx >> 3, ww = wdx & 7;
    const int i = n / kWS, j = n % kWS;
    const int hs = (wh * kWS + i + kSHIFT) % kH;   // roll by -3: rolled[h]=x[h+3]
    const int cs = (ww * kWS + j + kSHIFT) % kW;
    src = ((long)bb * kL + hs * kW + cs) * kDIM;
    dst = (long)r * kDIM;
  } else {
    src = (long)r * kDIM;
    dst = src;
  }
  const float v0 = x[src + lane];
  const float v1 = x[src + lane + 64];
  const float v2 = x[src + lane + 128];
  float s = v0 + v1 + v2;
  #pragma unroll
  for (int m = 1; m < 64; m <<= 1) s += __shfl_xor(s, m, 64);
  const float mu = s * (1.0f / 192.0f);
  const float d0 = v0 - mu, d1 = v1 - mu, d2 = v2 - mu;
  float vs = d0 * d0 + d1 * d1 + d2 * d2;
  #pragma unroll
  for (int m = 1; m < 64; m <<= 1) vs += __shfl_xor(vs, m, 64);
  const float inv = rsqrtf(vs * (1.0f / 192.0f) + 1e-5f);
  out[dst + lane]       = f2bf(d0 * inv * w[lane]       + b[lane]);
  out[dst + lane + 64]  = f2bf(d1 * inv * w[lane + 64]  + b[lane + 64]);
  out[dst + lane + 128] = f2bf(d2 * inv * w[lane + 128] + b[lane + 128]);
}

// ---------------- bf16 MFMA GEMM: C[r][c] = sum_k A[r][k]*W[c][k] (+epilogue) ----------------
// 128x64 block tile, 4 waves (2x2), each wave 64x32 = 4x2 fragments of 16x16.
// Fragments loaded straight from global (L2-resident, K small). fp32 accumulate.
// EPI 0: QKV  -> scatter bf16 q/k/v (window,head,token,d), q *= SCALE
// EPI 1: proj -> window-reverse + roll(+3) + residual(x fp32) -> out fp32
// EPI 2: FC1  -> exact GELU -> out bf16 (stride 768)
// EPI 3: FC2  -> + resid fp32 -> out fp32 (stride 192)
template<int KTOT, int EPI>
__global__ __launch_bounds__(256) void gemm_mfma(const u16* __restrict__ A,
                                                 const u16* __restrict__ Wt,
                                                 const float* __restrict__ bias,
                                                 const float* __restrict__ resid,
                                                 u16* __restrict__ out_bf,
                                                 float* __restrict__ out_f) {
  const int t    = threadIdx.x;
  const int wid  = t >> 6;
  const int lane = t & 63;
  const int wm   = wid >> 1;                       // 0..1
  const int wn   = wid & 1;                        // 0..1
  const int row0 = blockIdx.x * 128 + wm * 64;
  const int col0 = blockIdx.y * 64  + wn * 32;
  const int fr   = lane & 15;                      // A-row / B-col within fragment
  const int kg   = lane >> 4;                      // k-group (8 contiguous k each)

  f32x4 acc[4][2] = {};

  const u16* Ab = A  + (long)(row0 + fr) * KTOT + kg * 8;
  const u16* Wb = Wt + (long)(col0 + fr) * KTOT + kg * 8;
  for (int k0 = 0; k0 < KTOT; k0 += 32) {
    const bf16x8 a0 = *reinterpret_cast<const bf16x8*>(Ab + k0);
    const bf16x8 a1 = *reinterpret_cast<const bf16x8*>(Ab + 16L * KTOT + k0);
    const bf16x8 a2 = *reinterpret_cast<const bf16x8*>(Ab + 32L * KTOT + k0);
    const bf16x8 a3 = *reinterpret_cast<const bf16x8*>(Ab + 48L * KTOT + k0);
    const bf16x8 b0 = *reinterpret_cast<const bf16x8*>(Wb + k0);
    const bf16x8 b1 = *reinterpret_cast<const bf16x8*>(Wb + 16L * KTOT + k0);
    acc[0][0] = __builtin_amdgcn_mfma_f32_16x16x32_bf16(a0, b0, acc[0][0], 0, 0, 0);
    acc[0][1] = __builtin_amdgcn_mfma_f32_16x16x32_bf16(a0, b1, acc[0][1], 0, 0, 0);
    acc[1][0] = __builtin_amdgcn_mfma_f32_16x16x32_bf16(a1, b0, acc[1][0], 0, 0, 0);
    acc[1][1] = __builtin_amdgcn_mfma_f32_16x16x32_bf16(a1, b1, acc[1][1], 0, 0, 0);
    acc[2][0] = __builtin_amdgcn_mfma_f32_16x16x32_bf16(a2, b0, acc[2][0], 0, 0, 0);
    acc[2][1] = __builtin_amdgcn_mfma_f32_16x16x32_bf16(a2, b1, acc[2][1], 0, 0, 0);
    acc[3][0] = __builtin_amdgcn_mfma_f32_16x16x32_bf16(a3, b0, acc[3][0], 0, 0, 0);
    acc[3][1] = __builtin_amdgcn_mfma_f32_16x16x32_bf16(a3, b1, acc[3][1], 0, 0, 0);
  }

  // C element (fi,fj,r): row = row0+fi*16+kg*4+r, col = col0+fj*16+fr
  #pragma unroll
  for (int fi = 0; fi < 4; ++fi) {
    #pragma unroll
    for (int r = 0; r < 4; ++r) {
      const int row = row0 + fi * 16 + kg * 4 + r;
      if constexpr (EPI == 0) {
        const int bw = row / kN, n = row % kN;
        #pragma unroll
        for (int fj = 0; fj < 2; ++fj) {
          const int col = col0 + fj * 16 + fr;
          const int which = col / kDIM;           // 0=q 1=k 2=v
          const int cc = col - which * kDIM;
          const int hd = cc >> 5, d0 = cc & 31;
          float v = acc[fi][fj][r] + bias[col];
          if (which == 0) v *= kSCALE;
          out_bf[(long)which * SZf + (((long)bw * kNH + hd) * kN + n) * kHD + d0] = f2bf(v);
        }
      } else if constexpr (EPI == 1) {
        const int bw = row / kN, n = row % kN;
        const int bb = bw >> 6, wdx = bw & 63;
        const int wh = wdx >> 3, ww = wdx & 7;
        const int ii = n / kWS, jj = n % kWS;
        const int hf = (wh * kWS + ii + kSHIFT) % kH;   // roll back (+3)
        const int wf = (ww * kWS + jj + kSHIFT) % kW;
        const long dstr = ((long)bb * kL + hf * kW + wf) * kDIM;
        #pragma unroll
        for (int fj = 0; fj < 2; ++fj) {
          const int col = col0 + fj * 16 + fr;
          out_f[dstr + col] = resid[dstr + col] + acc[fi][fj][r] + bias[col];
        }
      } else if constexpr (EPI == 2) {
        #pragma unroll
        for (int fj = 0; fj < 2; ++fj) {
          const int col = col0 + fj * 16 + fr;
          float v = acc[fi][fj][r] + bias[col];
          v = 0.5f * v * (1.0f + erff(v * 0.7071067811865476f));
          out_bf[(long)row * kMLP + col] = f2bf(v);
        }
      } else {  // EPI == 3
        #pragma unroll
        for (int fj = 0; fj < 2; ++fj) {
          const int col = col0 + fj * 16 + fr;
          const long dst = (long)row * kDIM + col;
          out_f[dst] = resid[dst] + acc[fi][fj][r] + bias[col];
        }
      }
    }
  }
}

// ---------------- attention: one block per (window, head), bf16 I/O, fp32 math ----------------
__global__ __launch_bounds__(256) void attn_kernel(const u16* __restrict__ qkv,  // q|k|v, each SZf
                                                   const float* __restrict__ rpb, // (169, 6)
                                                   u16* __restrict__ out) {       // (Bw*49, 192) bf16
  __shared__ float qs[kN * 33];
  __shared__ float ks[kN * 33];
  __shared__ float vs[kN * 33];
  __shared__ float ss[kN * kN];
  const int bw   = blockIdx.x;
  const int head = blockIdx.y;
  const long base = ((long)bw * kNH + head) * (kN * kHD);
  const u16* qg = qkv + base;
  const u16* kg = qkv + SZf + base;
  const u16* vg = qkv + 2 * SZf + base;
  for (int g = threadIdx.x; g < kN * kHD; g += 256) {
    const int n = g >> 5, d = g & 31;
    qs[n * 33 + d] = bf2f(qg[g]);
    ks[n * 33 + d] = bf2f(kg[g]);
    vs[n * 33 + d] = bf2f(vg[g]);
  }
  __syncthreads();

  const int wdx = bw & 63;
  const int wh = wdx >> 3, ww = wdx & 7;

  // S = q k^T (+bias +mask)
  for (int e = threadIdx.x; e < kN * kN; e += 256) {
    const int n = e / kN, m = e % kN;
    float acc = 0.0f;
    #pragma unroll
    for (int d = 0; d < kHD; ++d) acc += qs[n * 33 + d] * ks[m * 33 + d];
    const int in_ = n / kWS, jn = n % kWS;
    const int im  = m / kWS, jm = m % kWS;
    acc += rpb[((in_ - im + 6) * 13 + (jn - jm + 6)) * kNH + head];
    const int hn = wh * kWS + in_, cn = ww * kWS + jn;
    const int hm = wh * kWS + im,  cm = ww * kWS + jm;
    const int lab_n = (hn < 49 ? 0 : (hn < 53 ? 1 : 2)) * 3 + (cn < 49 ? 0 : (cn < 53 ? 1 : 2));
    const int lab_m = (hm < 49 ? 0 : (hm < 53 ? 1 : 2)) * 3 + (cm < 49 ? 0 : (cm < 53 ? 1 : 2));
    if (lab_n != lab_m) acc -= 100.0f;
    ss[e] = acc;
  }
  __syncthreads();

  // softmax: one wave per row
  const int wave = threadIdx.x >> 6, lane = threadIdx.x & 63;
  for (int n = wave; n < kN; n += 4) {
    const float val = (lane < kN) ? ss[n * kN + lane] : -1e30f;
    float mx = val;
    #pragma unroll
    for (int m = 1; m < 64; m <<= 1) mx = fmaxf(mx, __shfl_xor(mx, m, 64));
    const float e = (lane < kN) ? __expf(val - mx) : 0.0f;
    float sum = e;
    #pragma unroll
    for (int m = 1; m < 64; m <<= 1) sum += __shfl_xor(sum, m, 64);
    if (lane < kN) ss[n * kN + lane] = e / sum;
  }
  __syncthreads();

  // O = P v  -> out bf16 at [(bw*49+n)*192 + head*32 + d]
  const int n0 = threadIdx.x >> 5, d = threadIdx.x & 31;
  for (int n = n0; n < kN; n += 8) {
    float acc = 0.0f;
    #pragma unroll
    for (int m = 0; m < kN; ++m) acc += ss[n * kN + m] * vs[m * 33 + d];
    out[((long)bw * kN + n) * kDIM + head * kHD + d] = f2bf(acc);
  }
}

// ---------------- launcher ----------------
// ws layout (u16 units), total 135,315,456 u16 = 258 MB:
//   [0*SZf) xw | [1..3]*SZf q,k,v | [4]*SZf attn_o | [5]*SZf h2 | [6]*SZf m1 (25088x768)
//   [7*SZf, +442368) bf16 weights: qkv|proj|fc1|fc2
extern "C" void kernel_launch(void* const* d_in, const int* in_sizes, int n_in,
                              void* d_out, int out_size, void* d_ws, size_t ws_size,
                              hipStream_t stream) {
  const float* x     = (const float*)d_in[0];
  const float* n1w   = (const float*)d_in[1];
  const float* n1b   = (const float*)d_in[2];
  const float* qkvw  = (const float*)d_in[3];
  const float* qkvb  = (const float*)d_in[4];
  const float* rpb   = (const float*)d_in[5];
  const float* projw = (const float*)d_in[6];
  const float* projb = (const float*)d_in[7];
  const float* n2w   = (const float*)d_in[8];
  const float* n2b   = (const float*)d_in[9];
  const float* fc1w  = (const float*)d_in[10];
  const float* fc1b  = (const float*)d_in[11];
  const float* fc2w  = (const float*)d_in[12];
  const float* fc2b  = (const float*)d_in[13];
  float* outp = (float*)d_out;
  u16*   wsu  = (u16*)d_ws;

  u16* xw     = wsu;
  u16* qb     = wsu + SZf;        // q,k,v (3 slots)
  u16* attn_o = wsu + 4 * SZf;
  u16* h2     = wsu + 5 * SZf;
  u16* m1     = wsu + 6 * SZf;    // 25088*768 = SZf elements
  u16* wts    = wsu + 7 * SZf;
  u16* wqkv   = wts;
  u16* wproj  = wts + 110592;
  u16* wfc1   = wts + 147456;
  u16* wfc2   = wts + 294912;

  // 0. weights -> bf16 (442368 elements)
  convert_weights<<<dim3(1728), dim3(256), 0, stream>>>(qkvw, projw, fc1w, fc2w, wts);
  // 1. LN1 + roll(-3,-3) + window partition -> bf16
  ln_kernel<true><<<dim3(kROWS / 4), dim3(256), 0, stream>>>(x, n1w, n1b, xw);
  // 2. QKV GEMM (MFMA) -> bf16 q/k/v scatter, q pre-scaled
  gemm_mfma<192, 0><<<dim3(kROWS / 128, 9), dim3(256), 0, stream>>>(xw, wqkv, qkvb, nullptr, qb, nullptr);
  // 3. attention per (window, head) -> bf16
  attn_kernel<<<dim3(kBw, kNH), dim3(256), 0, stream>>>(qb, rpb, attn_o);
  // 4. proj GEMM + window reverse + roll(+3,+3) + residual -> X1 fp32 (d_out)
  gemm_mfma<192, 1><<<dim3(kROWS / 128, 3), dim3(256), 0, stream>>>(attn_o, wproj, projb, x, nullptr, outp);
  // 5. LN2 -> bf16
  ln_kernel<false><<<dim3(kROWS / 4), dim3(256), 0, stream>>>(outp, n2w, n2b, h2);
  // 6+7. MLP in 4 row-chunks: FC1+GELU -> m1 bf16, FC2 + residual -> d_out fp32
  for (int c = 0; c < 4; ++c) {
    const long ro = (long)c * kCHUNK;
    gemm_mfma<192, 2><<<dim3(kCHUNK / 128, 12), dim3(256), 0, stream>>>(
        h2 + ro * kDIM, wfc1, fc1b, nullptr, m1, nullptr);
    gemm_mfma<768, 3><<<dim3(kCHUNK / 128, 3), dim3(256), 0, stream>>>(
        m1, wfc2, fc2b, outp + ro * kDIM, nullptr, outp + ro * kDIM);
  }
}

// Round 5
// 819.902 us; speedup vs baseline: 2.2417x; 1.2845x over previous
//
#include <hip/hip_runtime.h>
#include <math.h>

// ---------------- problem constants ----------------
constexpr int kDIM   = 192;
constexpr int kH     = 56;
constexpr int kW     = 56;
constexpr int kWS    = 7;
constexpr int kSHIFT = 3;
constexpr int kNH    = 6;
constexpr int kHD    = 32;            // DIM / NH
constexpr int kN     = 49;            // WS*WS
constexpr int kB     = 32;
constexpr int kL     = kH * kW;       // 3136
constexpr int kBw    = kB * 64;       // 2048 windows
constexpr int kROWS  = kBw * kN;      // 100352 = B*L
constexpr int kMLP   = 768;
constexpr int kCHUNK = kROWS / 4;     // 25088 rows per MLP chunk
constexpr float kSCALE = 0.17677669529663687f;   // 32^-0.5
constexpr long  SZf  = (long)kROWS * kDIM;       // 19,267,584 elements per slot

typedef unsigned short u16;
typedef __attribute__((ext_vector_type(8))) short bf16x8;   // 8 bf16 = 4 VGPRs
typedef __attribute__((ext_vector_type(4))) float f32x4;

__device__ __forceinline__ u16 f2bf(float f) {              // RNE float->bf16
  unsigned u = __float_as_uint(f);
  u += 0x7fff + ((u >> 16) & 1);
  return (u16)(u >> 16);
}
__device__ __forceinline__ float bf2f(u16 h) {
  return __uint_as_float(((unsigned)h) << 16);
}

// ---------------- weight conversion (fp32 -> bf16, all 4 mats) ----------------
__global__ __launch_bounds__(256) void convert_weights(const float* __restrict__ qkvw,
                                                       const float* __restrict__ projw,
                                                       const float* __restrict__ fc1w,
                                                       const float* __restrict__ fc2w,
                                                       u16* __restrict__ out) {
  const int i = blockIdx.x * 256 + threadIdx.x;   // total 442368
  float v;
  if (i < 110592)       v = qkvw[i];
  else if (i < 147456)  v = projw[i - 110592];
  else if (i < 294912)  v = fc1w[i - 147456];
  else                  v = fc2w[i - 294912];
  out[i] = f2bf(v);
}

// ---------------- bias+mask table: tbl[type][head][n][m], 64x64 each ----------------
// type = (wh==7)*2 + (ww==7). m>=49 -> -1e30 (pad col mask); n>=49 -> 0 (pad row, harmless).
__global__ __launch_bounds__(256) void build_table(const float* __restrict__ rpb,
                                                   float* __restrict__ tbl) {
  const int idx = blockIdx.x * 256 + threadIdx.x;  // < 98304 = 4*6*64*64
  const int m  = idx & 63;
  const int n  = (idx >> 6) & 63;
  const int th = idx >> 12;        // t*6 + h
  const int t = th / kNH, h = th % kNH;
  float v;
  if (m >= kN) v = -1e30f;
  else if (n >= kN) v = 0.0f;
  else {
    const int in_ = n / kWS, jn = n % kWS, im = m / kWS, jm = m % kWS;
    v = rpb[((in_ - im + 6) * 13 + (jn - jm + 6)) * kNH + h];
    const int whe = (t & 2) ? 7 : 0, wwe = (t & 1) ? 7 : 0;
    const int hn = whe * kWS + in_, cn = wwe * kWS + jn;
    const int hm = whe * kWS + im,  cm = wwe * kWS + jm;
    const int lab_n = (hn < 49 ? 0 : (hn < 53 ? 1 : 2)) * 3 + (cn < 49 ? 0 : (cn < 53 ? 1 : 2));
    const int lab_m = (hm < 49 ? 0 : (hm < 53 ? 1 : 2)) * 3 + (cm < 49 ? 0 : (cm < 53 ? 1 : 2));
    if (lab_n != lab_m) v -= 100.0f;
  }
  tbl[idx] = v;
}

// ---------------- LayerNorm -> bf16 (optionally fused roll + window partition) ----------------
template<bool GATHER>
__global__ __launch_bounds__(256) void ln_kernel(const float* __restrict__ x,
                                                 const float* __restrict__ w,
                                                 const float* __restrict__ b,
                                                 u16* __restrict__ out) {
  const int wave = threadIdx.x >> 6;
  const int lane = threadIdx.x & 63;
  const int r = blockIdx.x * 4 + wave;          // 0..100351
  long src, dst;
  if (GATHER) {
    const int bw = r / kN, n = r % kN;
    const int bb = bw >> 6, wdx = bw & 63;
    const int wh = wdx >> 3, ww = wdx & 7;
    const int i = n / kWS, j = n % kWS;
    const int hs = (wh * kWS + i + kSHIFT) % kH;   // roll by -3: rolled[h]=x[h+3]
    const int cs = (ww * kWS + j + kSHIFT) % kW;
    src = ((long)bb * kL + hs * kW + cs) * kDIM;
    dst = (long)r * kDIM;
  } else {
    src = (long)r * kDIM;
    dst = src;
  }
  const float v0 = x[src + lane];
  const float v1 = x[src + lane + 64];
  const float v2 = x[src + lane + 128];
  float s = v0 + v1 + v2;
  #pragma unroll
  for (int m = 1; m < 64; m <<= 1) s += __shfl_xor(s, m, 64);
  const float mu = s * (1.0f / 192.0f);
  const float d0 = v0 - mu, d1 = v1 - mu, d2 = v2 - mu;
  float vs = d0 * d0 + d1 * d1 + d2 * d2;
  #pragma unroll
  for (int m = 1; m < 64; m <<= 1) vs += __shfl_xor(vs, m, 64);
  const float inv = rsqrtf(vs * (1.0f / 192.0f) + 1e-5f);
  out[dst + lane]       = f2bf(d0 * inv * w[lane]       + b[lane]);
  out[dst + lane + 64]  = f2bf(d1 * inv * w[lane + 64]  + b[lane + 64]);
  out[dst + lane + 128] = f2bf(d2 * inv * w[lane + 128] + b[lane + 128]);
}

// ---------------- bf16 MFMA GEMM: C[r][c] = sum_k A[r][k]*W[c][k] (+epilogue) ----------------
template<int KTOT, int EPI>
__global__ __launch_bounds__(256) void gemm_mfma(const u16* __restrict__ A,
                                                 const u16* __restrict__ Wt,
                                                 const float* __restrict__ bias,
                                                 const float* __restrict__ resid,
                                                 u16* __restrict__ out_bf,
                                                 float* __restrict__ out_f) {
  const int t    = threadIdx.x;
  const int wid  = t >> 6;
  const int lane = t & 63;
  const int wm   = wid >> 1;                       // 0..1
  const int wn   = wid & 1;                        // 0..1
  const int row0 = blockIdx.x * 128 + wm * 64;
  const int col0 = blockIdx.y * 64  + wn * 32;
  const int fr   = lane & 15;                      // A-row / B-col within fragment
  const int kg   = lane >> 4;                      // k-group (8 contiguous k each)

  f32x4 acc[4][2] = {};

  const u16* Ab = A  + (long)(row0 + fr) * KTOT + kg * 8;
  const u16* Wb = Wt + (long)(col0 + fr) * KTOT + kg * 8;
  for (int k0 = 0; k0 < KTOT; k0 += 32) {
    const bf16x8 a0 = *reinterpret_cast<const bf16x8*>(Ab + k0);
    const bf16x8 a1 = *reinterpret_cast<const bf16x8*>(Ab + 16L * KTOT + k0);
    const bf16x8 a2 = *reinterpret_cast<const bf16x8*>(Ab + 32L * KTOT + k0);
    const bf16x8 a3 = *reinterpret_cast<const bf16x8*>(Ab + 48L * KTOT + k0);
    const bf16x8 b0 = *reinterpret_cast<const bf16x8*>(Wb + k0);
    const bf16x8 b1 = *reinterpret_cast<const bf16x8*>(Wb + 16L * KTOT + k0);
    acc[0][0] = __builtin_amdgcn_mfma_f32_16x16x32_bf16(a0, b0, acc[0][0], 0, 0, 0);
    acc[0][1] = __builtin_amdgcn_mfma_f32_16x16x32_bf16(a0, b1, acc[0][1], 0, 0, 0);
    acc[1][0] = __builtin_amdgcn_mfma_f32_16x16x32_bf16(a1, b0, acc[1][0], 0, 0, 0);
    acc[1][1] = __builtin_amdgcn_mfma_f32_16x16x32_bf16(a1, b1, acc[1][1], 0, 0, 0);
    acc[2][0] = __builtin_amdgcn_mfma_f32_16x16x32_bf16(a2, b0, acc[2][0], 0, 0, 0);
    acc[2][1] = __builtin_amdgcn_mfma_f32_16x16x32_bf16(a2, b1, acc[2][1], 0, 0, 0);
    acc[3][0] = __builtin_amdgcn_mfma_f32_16x16x32_bf16(a3, b0, acc[3][0], 0, 0, 0);
    acc[3][1] = __builtin_amdgcn_mfma_f32_16x16x32_bf16(a3, b1, acc[3][1], 0, 0, 0);
  }

  // C element (fi,fj,r): row = row0+fi*16+kg*4+r, col = col0+fj*16+fr
  #pragma unroll
  for (int fi = 0; fi < 4; ++fi) {
    #pragma unroll
    for (int r = 0; r < 4; ++r) {
      const int row = row0 + fi * 16 + kg * 4 + r;
      if constexpr (EPI == 0) {
        const int bw = row / kN, n = row % kN;
        #pragma unroll
        for (int fj = 0; fj < 2; ++fj) {
          const int col = col0 + fj * 16 + fr;
          const int which = col / kDIM;           // 0=q 1=k 2=v
          const int cc = col - which * kDIM;
          const int hd = cc >> 5, d0 = cc & 31;
          float v = acc[fi][fj][r] + bias[col];
          if (which == 0) v *= kSCALE;
          out_bf[(long)which * SZf + (((long)bw * kNH + hd) * kN + n) * kHD + d0] = f2bf(v);
        }
      } else if constexpr (EPI == 1) {
        const int bw = row / kN, n = row % kN;
        const int bb = bw >> 6, wdx = bw & 63;
        const int wh = wdx >> 3, ww = wdx & 7;
        const int ii = n / kWS, jj = n % kWS;
        const int hf = (wh * kWS + ii + kSHIFT) % kH;   // roll back (+3)
        const int wf = (ww * kWS + jj + kSHIFT) % kW;
        const long dstr = ((long)bb * kL + hf * kW + wf) * kDIM;
        #pragma unroll
        for (int fj = 0; fj < 2; ++fj) {
          const int col = col0 + fj * 16 + fr;
          out_f[dstr + col] = resid[dstr + col] + acc[fi][fj][r] + bias[col];
        }
      } else if constexpr (EPI == 2) {
        #pragma unroll
        for (int fj = 0; fj < 2; ++fj) {
          const int col = col0 + fj * 16 + fr;
          float v = acc[fi][fj][r] + bias[col];
          v = 0.5f * v * (1.0f + erff(v * 0.7071067811865476f));
          out_bf[(long)row * kMLP + col] = f2bf(v);
        }
      } else {  // EPI == 3
        #pragma unroll
        for (int fj = 0; fj < 2; ++fj) {
          const int col = col0 + fj * 16 + fr;
          const long dst = (long)row * kDIM + col;
          out_f[dst] = resid[dst] + acc[fi][fj][r] + bias[col];
        }
      }
    }
  }
}

// ---------------- MFMA attention: one wave per (window,head), 4 waves/block ----------------
// QK^T: A=Q,B=K frags from global (padded rows 49..63 read in-bounds garbage, masked by table).
// Softmax in-register (no max-sub: scores bounded, masked cols exp->0 exactly).
// P and V^T staged in LDS in fragment-order [kv_block][row][8] so PV reads are linear b128.
__global__ __launch_bounds__(256) void attn_mfma(const u16* __restrict__ qkv,   // q|k|v, each SZf
                                                 const float* __restrict__ tbl, // [4][6][64][64]
                                                 u16* __restrict__ out) {       // (Bw*49, 192) bf16
  __shared__ u16 lds[4][6144];     // per wave: pa 4096 (8KB) + vtt 2048 (4KB)
  const int wid  = threadIdx.x >> 6;
  const int lane = threadIdx.x & 63;
  u16* pa  = &lds[wid][0];         // P  [kvb 0..7][q 0..63][j 0..7]
  u16* vtt = &lds[wid][4096];      // V^T[kvb 0..7][d 0..31][j 0..7]
  const int pair = blockIdx.x * 4 + wid;       // = bw*6 + head
  const int bw = pair / kNH, head = pair % kNH;
  const int fr = lane & 15, kg = lane >> 4;
  const long base = (long)pair * (kN * kHD);
  const u16* qg = qkv + base;
  const u16* kp = qkv + SZf + base;
  const u16* vg = qkv + 2 * SZf + base;

  // zero vtt for kv = 49..63 (padding rows; kv=48 is real data written below)
  for (int i = lane; i < 480; i += 64) {       // 15 kv * 32 d
    const int kv = 49 + (i >> 5), d = i & 31;
    vtt[(kv >> 3) * 256 + d * 8 + (kv & 7)] = 0;
  }
  // stage V^T: 196 chunks of 8 contiguous elements
  for (int c = lane; c < 196; c += 64) {
    const bf16x8 v8 = *reinterpret_cast<const bf16x8*>(vg + c * 8);
    const int n = c >> 2, d0 = (c & 3) * 8;    // row n, cols d0..d0+7
    #pragma unroll
    for (int j = 0; j < 8; ++j)
      vtt[(n >> 3) * 256 + (d0 + j) * 8 + (n & 7)] = (u16)v8[j];
  }

  // QK^T fragments straight from global
  bf16x8 aq[4], bk[4];
  #pragma unroll
  for (int fi = 0; fi < 4; ++fi)
    aq[fi] = *reinterpret_cast<const bf16x8*>(qg + (fi * 16 + fr) * kHD + kg * 8);
  #pragma unroll
  for (int fj = 0; fj < 4; ++fj)
    bk[fj] = *reinterpret_cast<const bf16x8*>(kp + (fj * 16 + fr) * kHD + kg * 8);

  f32x4 s[4][4] = {};
  #pragma unroll
  for (int fi = 0; fi < 4; ++fi)
    #pragma unroll
    for (int fj = 0; fj < 4; ++fj)
      s[fi][fj] = __builtin_amdgcn_mfma_f32_16x16x32_bf16(aq[fi], bk[fj], s[fi][fj], 0, 0, 0);

  // bias+mask add (table), exp
  const int wh = (bw & 63) >> 3, ww = bw & 7;
  const int type = ((wh == 7) ? 2 : 0) | ((ww == 7) ? 1 : 0);
  const float* tb = tbl + ((long)type * kNH + head) * 4096;
  #pragma unroll
  for (int fi = 0; fi < 4; ++fi)
    #pragma unroll
    for (int fj = 0; fj < 4; ++fj)
      #pragma unroll
      for (int r = 0; r < 4; ++r) {
        const int row = fi * 16 + kg * 4 + r, col = fj * 16 + fr;
        s[fi][fj][r] = __expf(s[fi][fj][r] + tb[row * 64 + col]);
      }

  // row sums (16-lane group reduce) -> normalize -> write P to LDS (bf16)
  #pragma unroll
  for (int fi = 0; fi < 4; ++fi)
    #pragma unroll
    for (int r = 0; r < 4; ++r) {
      float rs = s[fi][0][r] + s[fi][1][r] + s[fi][2][r] + s[fi][3][r];
      #pragma unroll
      for (int m = 1; m < 16; m <<= 1) rs += __shfl_xor(rs, m, 64);
      const float rinv = __builtin_amdgcn_rcpf(rs);
      const int q = fi * 16 + kg * 4 + r;
      #pragma unroll
      for (int fj = 0; fj < 4; ++fj) {
        const int kv = fj * 16 + fr;
        pa[(kv >> 3) * 512 + q * 8 + (kv & 7)] = f2bf(s[fi][fj][r] * rinv);
      }
    }

  __syncthreads();   // LDS visibility (pa, vtt) — waves are independent but barrier is cheap

  // PV: D[q][d] = sum_kv P[q][kv] V[kv][d]
  f32x4 o[4][2] = {};
  #pragma unroll
  for (int ks = 0; ks < 2; ++ks) {
    bf16x8 pb[4], vb[2];
    #pragma unroll
    for (int fi = 0; fi < 4; ++fi)
      pb[fi] = *reinterpret_cast<const bf16x8*>(pa + (ks * 4 + kg) * 512 + (fi * 16 + fr) * 8);
    #pragma unroll
    for (int fjv = 0; fjv < 2; ++fjv)
      vb[fjv] = *reinterpret_cast<const bf16x8*>(vtt + (ks * 4 + kg) * 256 + (fjv * 16 + fr) * 8);
    #pragma unroll
    for (int fi = 0; fi < 4; ++fi)
      #pragma unroll
      for (int fjv = 0; fjv < 2; ++fjv)
        o[fi][fjv] = __builtin_amdgcn_mfma_f32_16x16x32_bf16(pb[fi], vb[fjv], o[fi][fjv], 0, 0, 0);
  }

  // store rows q < 49
  #pragma unroll
  for (int fi = 0; fi < 4; ++fi)
    #pragma unroll
    for (int r = 0; r < 4; ++r) {
      const int q = fi * 16 + kg * 4 + r;
      if (q < kN) {
        const long dst = ((long)bw * kN + q) * kDIM + head * kHD;
        #pragma unroll
        for (int fjv = 0; fjv < 2; ++fjv)
          out[dst + fjv * 16 + fr] = f2bf(o[fi][fjv][r]);
      }
    }
}

// ---------------- launcher ----------------
// ws layout (u16 units):
//   [0..7)*SZf : xw | q | k | v | attn_o | h2 | m1 | weights(442368) + table(98304 f32)
extern "C" void kernel_launch(void* const* d_in, const int* in_sizes, int n_in,
                              void* d_out, int out_size, void* d_ws, size_t ws_size,
                              hipStream_t stream) {
  const float* x     = (const float*)d_in[0];
  const float* n1w   = (const float*)d_in[1];
  const float* n1b   = (const float*)d_in[2];
  const float* qkvw  = (const float*)d_in[3];
  const float* qkvb  = (const float*)d_in[4];
  const float* rpb   = (const float*)d_in[5];
  const float* projw = (const float*)d_in[6];
  const float* projb = (const float*)d_in[7];
  const float* n2w   = (const float*)d_in[8];
  const float* n2b   = (const float*)d_in[9];
  const float* fc1w  = (const float*)d_in[10];
  const float* fc1b  = (const float*)d_in[11];
  const float* fc2w  = (const float*)d_in[12];
  const float* fc2b  = (const float*)d_in[13];
  float* outp = (float*)d_out;
  u16*   wsu  = (u16*)d_ws;

  u16* xw     = wsu;
  u16* qb     = wsu + SZf;        // q,k,v (3 slots)
  u16* attn_o = wsu + 4 * SZf;
  u16* h2     = wsu + 5 * SZf;
  u16* m1     = wsu + 6 * SZf;    // 25088*768 = SZf elements
  u16* wts    = wsu + 7 * SZf;
  u16* wqkv   = wts;
  u16* wproj  = wts + 110592;
  u16* wfc1   = wts + 147456;
  u16* wfc2   = wts + 294912;
  float* tbl  = (float*)(wts + 442368);   // 98304 floats

  // 0. weights -> bf16; bias+mask table
  convert_weights<<<dim3(1728), dim3(256), 0, stream>>>(qkvw, projw, fc1w, fc2w, wts);
  build_table<<<dim3(384), dim3(256), 0, stream>>>(rpb, tbl);
  // 1. LN1 + roll(-3,-3) + window partition -> bf16
  ln_kernel<true><<<dim3(kROWS / 4), dim3(256), 0, stream>>>(x, n1w, n1b, xw);
  // 2. QKV GEMM (MFMA) -> bf16 q/k/v scatter, q pre-scaled
  gemm_mfma<192, 0><<<dim3(kROWS / 128, 9), dim3(256), 0, stream>>>(xw, wqkv, qkvb, nullptr, qb, nullptr);
  // 3. MFMA attention, one wave per (window, head)
  attn_mfma<<<dim3(kBw * kNH / 4), dim3(256), 0, stream>>>(qb, tbl, attn_o);
  // 4. proj GEMM + window reverse + roll(+3,+3) + residual -> X1 fp32 (d_out)
  gemm_mfma<192, 1><<<dim3(kROWS / 128, 3), dim3(256), 0, stream>>>(attn_o, wproj, projb, x, nullptr, outp);
  // 5. LN2 -> bf16
  ln_kernel<false><<<dim3(kROWS / 4), dim3(256), 0, stream>>>(outp, n2w, n2b, h2);
  // 6+7. MLP in 4 row-chunks: FC1+GELU -> m1 bf16, FC2 + residual -> d_out fp32
  for (int c = 0; c < 4; ++c) {
    const long ro = (long)c * kCHUNK;
    gemm_mfma<192, 2><<<dim3(kCHUNK / 128, 12), dim3(256), 0, stream>>>(
        h2 + ro * kDIM, wfc1, fc1b, nullptr, m1, nullptr);
    gemm_mfma<768, 3><<<dim3(kCHUNK / 128, 3), dim3(256), 0, stream>>>(
        m1, wfc2, fc2b, outp + ro * kDIM, nullptr, outp + ro * kDIM);
  }
}